// Round 1
// baseline (347.948 us; speedup 1.0000x reference)
//
#include <hip/hip_runtime.h>
#include <hip/hip_bf16.h>
#include <math.h>

// SpikingNeuralNetwork: 3 chained bf16-MFMA GEMMs + fused elementwise epilogues.
// N = 2048 everywhere.

#define NN 2048
#define NT (NN / 128)   // 16 tiles per dim

typedef __attribute__((ext_vector_type(8))) short bf16x8;
typedef __attribute__((ext_vector_type(4))) float f32x4;
typedef __attribute__((ext_vector_type(4))) short s16x4;

__device__ __forceinline__ short f2bf(float f) {
    union { float f; unsigned u; } a; a.f = f;
    unsigned r = a.u + 0x7FFFu + ((a.u >> 16) & 1u);   // RNE
    return (short)(r >> 16);
}

__device__ __forceinline__ void gload16(const short* g, short* l) {
    __builtin_amdgcn_global_load_lds(
        (const __attribute__((address_space(1))) unsigned int*)g,
        (__attribute__((address_space(3))) unsigned int*)l, 16, 0, 0);
}

__device__ __forceinline__ float sigmoidf_(float x) {
    return 1.0f / (1.0f + expf(-x));
}

// ---------------- f32 -> bf16 conversion (vectorized) ----------------
__global__ void conv_kernel(const float* __restrict__ src, short* __restrict__ dst) {
    int i = blockIdx.x * blockDim.x + threadIdx.x;   // over NN*NN/4
    float4 v = reinterpret_cast<const float4*>(src)[i];
    s16x4 o;
    o.x = f2bf(v.x); o.y = f2bf(v.y); o.z = f2bf(v.z); o.w = f2bf(v.w);
    reinterpret_cast<s16x4*>(dst)[i] = o;
}

__global__ void zero_flags_kernel(int* flags) {
    flags[blockIdx.x * blockDim.x + threadIdx.x] = 0;
}

// ---------------- fused GEMM (C = A @ B^T, A:[M,K] bf16, B:[N,K] bf16) ----------------
// EPI 1: v = 0.5*mp + sigmoid(acc+b1); spike detect/reset; write v_bf16, n/m/h outs, flags
// EPI 2: write bf16 sigmoid(acc+b2)
// EPI 3: write f32  sigmoid(acc+b3)
template <int EPI>
__global__ __launch_bounds__(256) void gemm_fused(
    const short* __restrict__ A, const short* __restrict__ B,
    const float* __restrict__ bias,
    const float* __restrict__ mp,
    const float* __restrict__ n_in, const float* __restrict__ m_in,
    const float* __restrict__ h_in,
    short* __restrict__ out_bf, float* __restrict__ out_f,
    float* __restrict__ out_n, float* __restrict__ out_m,
    float* __restrict__ out_h,
    int* __restrict__ flags)
{
    __shared__ short As[128 * 32] __attribute__((aligned(16)));
    __shared__ short Bs[128 * 32] __attribute__((aligned(16)));

    const int tid  = threadIdx.x;
    const int lane = tid & 63;
    const int wid  = tid >> 6;
    const int row0 = blockIdx.y * 128;
    const int col0 = blockIdx.x * 128;
    const int wm = (wid >> 1) * 64;     // wave's sub-tile origin in M
    const int wn = (wid & 1) * 64;      // in N
    const int lrow = lane & 15;
    const int lk   = (lane >> 4) << 3;  // k offset 0/8/16/24

    f32x4 acc[4][4] = {};

    for (int k0 = 0; k0 < NN; k0 += 32) {
        // stage A-tile [128][32] and B-tile [128][32] (both row-major, linear LDS)
#pragma unroll
        for (int s = 0; s < 2; ++s) {
            int c  = tid + s * 256;       // 16B chunk id, 512 chunks per tile
            int r  = c >> 2;              // row within tile
            int ko = (c & 3) << 3;        // k offset (bf16 elems)
            gload16(A + (size_t)(row0 + r) * NN + k0 + ko, As + c * 8);
            gload16(B + (size_t)(col0 + r) * NN + k0 + ko, Bs + c * 8);
        }
        __syncthreads();   // compiler emits vmcnt(0) drain before s_barrier

        bf16x8 af[4], bfr[4];
#pragma unroll
        for (int i = 0; i < 4; ++i)
            af[i] = *reinterpret_cast<const bf16x8*>(As + (wm + i * 16 + lrow) * 32 + lk);
#pragma unroll
        for (int j = 0; j < 4; ++j)
            bfr[j] = *reinterpret_cast<const bf16x8*>(Bs + (wn + j * 16 + lrow) * 32 + lk);

#pragma unroll
        for (int i = 0; i < 4; ++i)
#pragma unroll
            for (int j = 0; j < 4; ++j)
                acc[i][j] = __builtin_amdgcn_mfma_f32_16x16x32_bf16(af[i], bfr[j], acc[i][j], 0, 0, 0);
        __syncthreads();
    }

    // epilogue — C/D layout: col = lane&15, row = (lane>>4)*4 + reg
#pragma unroll
    for (int i = 0; i < 4; ++i) {
#pragma unroll
        for (int j = 0; j < 4; ++j) {
            const int gcol = col0 + wn + j * 16 + lrow;
#pragma unroll
            for (int r = 0; r < 4; ++r) {
                const int grow = row0 + wm + i * 16 + ((lane >> 4) << 2) + r;
                const size_t idx = (size_t)grow * NN + gcol;
                float pre = acc[i][j][r] + bias[gcol];
                float sg  = sigmoidf_(pre);
                if constexpr (EPI == 1) {
                    float v = 0.5f * mp[gcol] + sg;
                    if (v > 1.0f) { flags[grow] = 1; v = 0.0f; }
                    out_bf[idx] = f2bf(v);
                    float an = 0.01f * (v + 55.0f) / (1.0f - expf(-(v + 55.0f) / 10.0f));
                    float bn = 0.125f * expf(-(v + 65.0f) / 80.0f);
                    float am = 0.1f  * (v + 40.0f) / (1.0f - expf(-(v + 40.0f) / 10.0f));
                    float bm = 4.0f  * expf(-(v + 65.0f) / 18.0f);
                    float ah = 0.07f * expf(-(v + 65.0f) / 20.0f);
                    float bh = 1.0f  / (1.0f + expf(-(v + 35.0f) / 10.0f));
                    float nv = n_in[gcol], mv = m_in[gcol], hv = h_in[gcol];
                    out_n[idx] = nv + 0.01f * (an * (1.0f - nv) - bn * nv);
                    out_m[idx] = mv + 0.01f * (am * (1.0f - mv) - bm * mv);
                    out_h[idx] = hv + 0.01f * (ah * (1.0f - hv) - bh * hv);
                } else if constexpr (EPI == 2) {
                    out_bf[idx] = f2bf(sg);
                } else {
                    out_f[idx] = sg;
                }
            }
        }
    }
}

// ---------------- STDP weight update ----------------
__global__ void stdp_kernel(const float* __restrict__ w, const float* __restrict__ lst,
                            const int* __restrict__ flags, float* __restrict__ outw)
{
    int idx = blockIdx.x * blockDim.x + threadIdx.x;  // over NN*NN/4
    int i  = idx >> 9;            // row  (NN/4 = 512 float4 per row)
    int j4 = (idx & 511) << 2;    // first col of the group
    float4 wv = reinterpret_cast<const float4*>(w)[idx];
    float o[4] = {wv.x, wv.y, wv.z, wv.w};
    const int   rsi = flags[i];
    const float tsi = 10.0f - lst[i];
#pragma unroll
    for (int t = 0; t < 4; ++t) {
        int j = j4 + t;
        if (rsi | flags[j]) {
            float dtm = tsi - (10.0f - lst[j]);
            float dw = (dtm > 0.0f) ? (-0.015f * expf(-fabsf(dtm) / 25.0f))
                                    : ( 0.02f  * expf(-fabsf(dtm) / 15.0f));
            o[t] += dw;
        }
        o[t] = fminf(1.0f, fmaxf(-1.0f, o[t]));
    }
    float4 ov = make_float4(o[0], o[1], o[2], o[3]);
    reinterpret_cast<float4*>(outw)[idx] = ov;
}

extern "C" void kernel_launch(void* const* d_in, const int* in_sizes, int n_in,
                              void* d_out, int out_size, void* d_ws, size_t ws_size,
                              hipStream_t stream)
{
    const float* x   = (const float*)d_in[0];
    const float* W1  = (const float*)d_in[1];
    const float* b1  = (const float*)d_in[2];
    const float* W2  = (const float*)d_in[3];
    const float* b2  = (const float*)d_in[4];
    const float* W3  = (const float*)d_in[5];
    const float* b3  = (const float*)d_in[6];
    const float* wts = (const float*)d_in[7];
    const float* lst = (const float*)d_in[8];
    const float* mp  = (const float*)d_in[9];
    const float* nin = (const float*)d_in[10];
    const float* min_ = (const float*)d_in[11];
    const float* hin = (const float*)d_in[12];

    const size_t NSQ = (size_t)NN * NN;
    float* out    = (float*)d_out;          // [N,N] final MLP output
    float* out_w  = out + NSQ;              // new_weights
    float* out_n  = out + 2 * NSQ;
    float* out_m  = out + 3 * NSQ;
    float* out_h  = out + 4 * NSQ;

    short* xb  = (short*)d_ws;
    short* w1b = xb  + NSQ;
    short* w2b = w1b + NSQ;
    short* w3b = w2b + NSQ;
    short* vb  = w3b + NSQ;
    short* h1b = vb  + NSQ;
    int*   flags = (int*)(h1b + NSQ);

    const int convBlocks = (int)(NSQ / 4 / 256);   // 4096

    zero_flags_kernel<<<NN / 256, 256, 0, stream>>>(flags);
    conv_kernel<<<convBlocks, 256, 0, stream>>>(x,  xb);
    conv_kernel<<<convBlocks, 256, 0, stream>>>(W1, w1b);
    conv_kernel<<<convBlocks, 256, 0, stream>>>(W2, w2b);
    conv_kernel<<<convBlocks, 256, 0, stream>>>(W3, w3b);

    dim3 grid(NT, NT);
    // GEMM1: v/HH/spike epilogue
    gemm_fused<1><<<grid, 256, 0, stream>>>(xb, w1b, b1, mp, nin, min_, hin,
                                            vb, nullptr, out_n, out_m, out_h, flags);
    // STDP weights (needs row flags from GEMM1)
    stdp_kernel<<<convBlocks, 256, 0, stream>>>(wts, lst, flags, out_w);
    // GEMM2: h1 = sigmoid(v@W2^T+b2) -> bf16
    gemm_fused<2><<<grid, 256, 0, stream>>>(vb, w2b, b2, nullptr, nullptr, nullptr, nullptr,
                                            h1b, nullptr, nullptr, nullptr, nullptr, nullptr);
    // GEMM3: out = sigmoid(h1@W3^T+b3) -> f32
    gemm_fused<3><<<grid, 256, 0, stream>>>(h1b, w3b, b3, nullptr, nullptr, nullptr, nullptr,
                                            nullptr, out, nullptr, nullptr, nullptr, nullptr);
}

// Round 2
// 157.267 us; speedup vs baseline: 2.2125x; 2.2125x over previous
//
#include <hip/hip_runtime.h>
#include <hip/hip_bf16.h>
#include <math.h>

// SpikingNeuralNetwork: 3 chained bf16-MFMA GEMMs + fused elementwise epilogues.
// N = 2048. Round 2: 2-phase double-buffered K-loop (BK=64), LDS XOR swizzle,
// 8 waves/block, merged conversion kernel.

#define NN 2048
#define BK 64
#define NT (NN / 128)   // 16 tiles per dim

typedef __attribute__((ext_vector_type(8))) short bf16x8;
typedef __attribute__((ext_vector_type(4))) float f32x4;
typedef __attribute__((ext_vector_type(4))) short s16x4;

__device__ __forceinline__ short f2bf(float f) {
    union { float f; unsigned u; } a; a.f = f;
    unsigned r = a.u + 0x7FFFu + ((a.u >> 16) & 1u);   // RNE
    return (short)(r >> 16);
}

__device__ __forceinline__ void gload16(const short* g, short* l) {
    __builtin_amdgcn_global_load_lds(
        (const __attribute__((address_space(1))) unsigned int*)g,
        (__attribute__((address_space(3))) unsigned int*)l, 16, 0, 0);
}

__device__ __forceinline__ float sigmoidf_(float x) {
    return 1.0f / (1.0f + expf(-x));
}

// ---------------- f32 -> bf16 conversion (4 arrays in one launch) ----------------
__global__ void conv4_kernel(const float* __restrict__ s0, const float* __restrict__ s1,
                             const float* __restrict__ s2, const float* __restrict__ s3,
                             short* __restrict__ d0, short* __restrict__ d1,
                             short* __restrict__ d2, short* __restrict__ d3,
                             int* __restrict__ flags)
{
    const float* src; short* dst;
    if      (blockIdx.y == 0) { src = s0; dst = d0; }
    else if (blockIdx.y == 1) { src = s1; dst = d1; }
    else if (blockIdx.y == 2) { src = s2; dst = d2; }
    else                      { src = s3; dst = d3; }
    int i = blockIdx.x * blockDim.x + threadIdx.x;   // over NN*NN/4
    float4 v = reinterpret_cast<const float4*>(src)[i];
    s16x4 o;
    o.x = f2bf(v.x); o.y = f2bf(v.y); o.z = f2bf(v.z); o.w = f2bf(v.w);
    reinterpret_cast<s16x4*>(dst)[i] = o;
    if (blockIdx.y == 0 && blockIdx.x < NN / 256)
        flags[blockIdx.x * blockDim.x + threadIdx.x] = 0;
}

// ---------------- fused GEMM (C = A @ B^T, A:[M,K] bf16, B:[N,K] bf16) ----------------
// 128x128 tile, 8 waves (2x4), BK=64, double-buffered LDS, XOR-swizzled layout.
// EPI 1: v = 0.5*mp + sigmoid(acc+b1); spike detect/reset; v_bf16, n/m/h outs, flags
// EPI 2: bf16 sigmoid(acc+b2)
// EPI 3: f32  sigmoid(acc+b3)
template <int EPI>
__global__ __launch_bounds__(512) void gemm_fused(
    const short* __restrict__ A, const short* __restrict__ B,
    const float* __restrict__ bias,
    const float* __restrict__ mp,
    const float* __restrict__ n_in, const float* __restrict__ m_in,
    const float* __restrict__ h_in,
    short* __restrict__ out_bf, float* __restrict__ out_f,
    float* __restrict__ out_n, float* __restrict__ out_m,
    float* __restrict__ out_h,
    int* __restrict__ flags)
{
    __shared__ short As[2][128 * BK] __attribute__((aligned(16)));
    __shared__ short Bs[2][128 * BK] __attribute__((aligned(16)));

    const int tid  = threadIdx.x;
    const int lane = tid & 63;
    const int wid  = tid >> 6;          // 0..7
    const int row0 = blockIdx.y * 128;
    const int col0 = blockIdx.x * 128;
    const int wm   = (wid >> 2) * 64;   // wave sub-tile origin in M (0/64)
    const int wn   = (wid & 3) * 32;    // in N (0/32/64/96)
    const int lrow = lane & 15;
    const int lk16 = (lane >> 4) << 3;  // 0/8/16/24

    f32x4 acc[4][2] = {};

    // Stage one K-64 tile pair into buffer `buf`.
    // LDS dest is linear (chunk c -> bytes c*16); global source is
    // inverse-swizzled so that a swizzled ds_read returns linear data.
    auto stage = [&](int buf, int k0) {
#pragma unroll
        for (int s = 0; s < 2; ++s) {
            int c = tid + s * 512;                       // chunk id 0..1023
            int r = c >> 3;                              // row in tile
            int ksrc = ((c & 7) ^ (r & 7)) << 3;         // swizzled k (bf16 elems)
            gload16(A + (size_t)(row0 + r) * NN + k0 + ksrc, &As[buf][c * 8]);
            gload16(B + (size_t)(col0 + r) * NN + k0 + ksrc, &Bs[buf][c * 8]);
        }
    };

    auto compute = [&](int buf) {
        bf16x8 af[4][2], bfv[2][2];
#pragma unroll
        for (int i = 0; i < 4; ++i) {
            const int row = wm + i * 16 + lrow;
#pragma unroll
            for (int kk = 0; kk < 2; ++kk) {
                const int ke = (lk16 + kk * 32) ^ ((row & 7) << 3);
                af[i][kk] = *reinterpret_cast<const bf16x8*>(&As[buf][row * BK + ke]);
            }
        }
#pragma unroll
        for (int j = 0; j < 2; ++j) {
            const int row = wn + j * 16 + lrow;
#pragma unroll
            for (int kk = 0; kk < 2; ++kk) {
                const int ke = (lk16 + kk * 32) ^ ((row & 7) << 3);
                bfv[j][kk] = *reinterpret_cast<const bf16x8*>(&Bs[buf][row * BK + ke]);
            }
        }
#pragma unroll
        for (int kk = 0; kk < 2; ++kk)
#pragma unroll
            for (int i = 0; i < 4; ++i)
#pragma unroll
                for (int j = 0; j < 2; ++j)
                    acc[i][j] = __builtin_amdgcn_mfma_f32_16x16x32_bf16(
                        af[i][kk], bfv[j][kk], acc[i][j], 0, 0, 0);
    };

    // 2-phase pipeline: STAGE(next) issued before compute(cur); single
    // vmcnt(0)+barrier per iteration (emitted by __syncthreads()).
    stage(0, 0);
    __syncthreads();
    int cur = 0;
    for (int t = 0; t < NN / BK - 1; ++t) {
        stage(cur ^ 1, (t + 1) * BK);
        compute(cur);
        __syncthreads();
        cur ^= 1;
    }
    compute(cur);

    // epilogue — C/D layout: col = lane&15, row = (lane>>4)*4 + reg
#pragma unroll
    for (int i = 0; i < 4; ++i) {
#pragma unroll
        for (int j = 0; j < 2; ++j) {
            const int gcol = col0 + wn + j * 16 + lrow;
#pragma unroll
            for (int r = 0; r < 4; ++r) {
                const int grow = row0 + wm + i * 16 + ((lane >> 4) << 2) + r;
                const size_t idx = (size_t)grow * NN + gcol;
                float pre = acc[i][j][r] + bias[gcol];
                float sg  = sigmoidf_(pre);
                if constexpr (EPI == 1) {
                    float v = 0.5f * mp[gcol] + sg;
                    if (v > 1.0f) { flags[grow] = 1; v = 0.0f; }
                    out_bf[idx] = f2bf(v);
                    float an = 0.01f * (v + 55.0f) / (1.0f - expf(-(v + 55.0f) / 10.0f));
                    float bn = 0.125f * expf(-(v + 65.0f) / 80.0f);
                    float am = 0.1f  * (v + 40.0f) / (1.0f - expf(-(v + 40.0f) / 10.0f));
                    float bm = 4.0f  * expf(-(v + 65.0f) / 18.0f);
                    float ah = 0.07f * expf(-(v + 65.0f) / 20.0f);
                    float bh = 1.0f  / (1.0f + expf(-(v + 35.0f) / 10.0f));
                    float nv = n_in[gcol], mv = m_in[gcol], hv = h_in[gcol];
                    out_n[idx] = nv + 0.01f * (an * (1.0f - nv) - bn * nv);
                    out_m[idx] = mv + 0.01f * (am * (1.0f - mv) - bm * mv);
                    out_h[idx] = hv + 0.01f * (ah * (1.0f - hv) - bh * hv);
                } else if constexpr (EPI == 2) {
                    out_bf[idx] = f2bf(sg);
                } else {
                    out_f[idx] = sg;
                }
            }
        }
    }
}

// ---------------- STDP weight update ----------------
__global__ void stdp_kernel(const float* __restrict__ w, const float* __restrict__ lst,
                            const int* __restrict__ flags, float* __restrict__ outw)
{
    int idx = blockIdx.x * blockDim.x + threadIdx.x;  // over NN*NN/4
    int i  = idx >> 9;            // row  (NN/4 = 512 float4 per row)
    int j4 = (idx & 511) << 2;    // first col of the group
    float4 wv = reinterpret_cast<const float4*>(w)[idx];
    float o[4] = {wv.x, wv.y, wv.z, wv.w};
    const int   rsi = flags[i];
    const float tsi = 10.0f - lst[i];
#pragma unroll
    for (int t = 0; t < 4; ++t) {
        int j = j4 + t;
        if (rsi | flags[j]) {
            float dtm = tsi - (10.0f - lst[j]);
            float dw = (dtm > 0.0f) ? (-0.015f * expf(-fabsf(dtm) / 25.0f))
                                    : ( 0.02f  * expf(-fabsf(dtm) / 15.0f));
            o[t] += dw;
        }
        o[t] = fminf(1.0f, fmaxf(-1.0f, o[t]));
    }
    float4 ov = make_float4(o[0], o[1], o[2], o[3]);
    reinterpret_cast<float4*>(outw)[idx] = ov;
}

extern "C" void kernel_launch(void* const* d_in, const int* in_sizes, int n_in,
                              void* d_out, int out_size, void* d_ws, size_t ws_size,
                              hipStream_t stream)
{
    const float* x   = (const float*)d_in[0];
    const float* W1  = (const float*)d_in[1];
    const float* b1  = (const float*)d_in[2];
    const float* W2  = (const float*)d_in[3];
    const float* b2  = (const float*)d_in[4];
    const float* W3  = (const float*)d_in[5];
    const float* b3  = (const float*)d_in[6];
    const float* wts = (const float*)d_in[7];
    const float* lst = (const float*)d_in[8];
    const float* mp  = (const float*)d_in[9];
    const float* nin = (const float*)d_in[10];
    const float* min_ = (const float*)d_in[11];
    const float* hin = (const float*)d_in[12];

    const size_t NSQ = (size_t)NN * NN;
    float* out    = (float*)d_out;          // [N,N] final MLP output
    float* out_w  = out + NSQ;              // new_weights
    float* out_n  = out + 2 * NSQ;
    float* out_m  = out + 3 * NSQ;
    float* out_h  = out + 4 * NSQ;

    short* xb  = (short*)d_ws;
    short* w1b = xb  + NSQ;
    short* w2b = w1b + NSQ;
    short* w3b = w2b + NSQ;
    short* vb  = w3b + NSQ;
    short* h1b = vb  + NSQ;
    int*   flags = (int*)(h1b + NSQ);

    const int convBlocks = (int)(NSQ / 4 / 256);   // 4096 per array

    conv4_kernel<<<dim3(convBlocks, 4), 256, 0, stream>>>(x, W1, W2, W3,
                                                          xb, w1b, w2b, w3b, flags);

    dim3 grid(NT, NT);
    // GEMM1: v/HH/spike epilogue
    gemm_fused<1><<<grid, 512, 0, stream>>>(xb, w1b, b1, mp, nin, min_, hin,
                                            vb, nullptr, out_n, out_m, out_h, flags);
    // STDP weights (needs row flags from GEMM1)
    stdp_kernel<<<convBlocks, 256, 0, stream>>>(wts, lst, flags, out_w);
    // GEMM2: h1 = sigmoid(v@W2^T+b2) -> bf16
    gemm_fused<2><<<grid, 512, 0, stream>>>(vb, w2b, b2, nullptr, nullptr, nullptr, nullptr,
                                            h1b, nullptr, nullptr, nullptr, nullptr, nullptr);
    // GEMM3: out = sigmoid(h1@W3^T+b3) -> f32
    gemm_fused<3><<<grid, 512, 0, stream>>>(h1b, w3b, b3, nullptr, nullptr, nullptr, nullptr,
                                            nullptr, out, nullptr, nullptr, nullptr, nullptr);
}